// Round 5
// baseline (153.444 us; speedup 1.0000x reference)
//
#include <hip/hip_runtime.h>

// Batched 2D db4 DWT (pywt dwt2, mode='symmetric') over [8,32,512,512] f32.
// Output [4, 8, 32, 259, 259] f32 (LL, LH, HL, HH).
//
//   y[o] = sum_k ext[2o+1+k] * G[k],  G[k] = F[7-k]
//   ext index j -> src:  j<7 -> 6-j ; j<=518 -> j-7 ; else 1030-j
//
// v5: register-ring walker like v4, but thread = 2 output cols (NCG=130),
// doubling waves (11,440 ~= 1.8x resident capacity -> backfill) at unchanged
// FMA/output and unchanged vertical halo (30/24). Per-row window = 12 floats,
// 16B-aligned (base 4*cg-8; edge-clamped bases 0/500 also aligned) -> 3x
// aligned float4 loads. Reflection-straddling cols cg in {0,1,128,129} use
// static register permutations. No LDS, no barriers.

namespace {

constexpr int N   = 512;
constexpr int HO  = 259;
constexpr int NBC = 256;
constexpr int TOH = 12;                     // output rows per strip
constexpr int NS  = 22;                     // strips (22*12 = 264 >= 259)
constexpr int NCG = 130;                    // 2-col groups (130*2 = 260 >= 259)

typedef float f4 __attribute__((ext_vector_type(4)));
typedef float f2 __attribute__((ext_vector_type(2)));
typedef f2 __attribute__((aligned(4))) f2u;

__device__ constexpr float GL[8] = {
     0.23037781330885523f,  0.7148465705525415f,   0.6308807679295904f,
    -0.02798376941698385f, -0.18703481171888114f,  0.030841381835986965f,
     0.032883011666982945f,-0.010597401784997278f};
__device__ constexpr float GH[8] = {
    -0.010597401784997278f,-0.032883011666982945f, 0.030841381835986965f,
     0.18703481171888114f, -0.02798376941698385f, -0.6308807679295904f,
     0.7148465705525415f,  -0.23037781330885523f};

// Tap -> 12-float-window permutations. Window loaded from clamped base
// gb = clamp(4*cg-8, 0, 500); tap f reads ext[2*c0+1+f].
__device__ constexpr int IMAP[10] = {2,3,4,5,6,7,8,9,10,11};      // interior
__device__ constexpr int LM0[10] = {5,4,3,2,1,0,0,1,2,3};         // cg==0   (gb=0)
__device__ constexpr int LM1[10] = {1,0,0,1,2,3,4,5,6,7};         // cg==1   (gb=0)
__device__ constexpr int RM0[10] = {6,7,8,9,10,11,11,10,9,8};     // cg==128 (gb=500)
__device__ constexpr int RM1[10] = {10,11,11,10,9,8,7,6,5,4};     // cg==129 (gb=500)

__device__ __forceinline__ int ext_row(int j) {
    int v = j - 7;
    v = (j < 7)     ? (6 - j)         : v;
    v = (j > N + 6) ? (2 * N + 6 - j) : v;
    return v;
}

__device__ __forceinline__ void hconv(const float* __restrict__ base, int mode,
                                      f2& lo, f2& hi) {
    const f4 a = *(const f4*)(base);
    const f4 b = *(const f4*)(base + 4);
    const f4 c = *(const f4*)(base + 8);
    const float win[12] = {a.x,a.y,a.z,a.w, b.x,b.y,b.z,b.w, c.x,c.y,c.z,c.w};
    float v[10];
    switch (mode) {
    case 0:
        #pragma unroll
        for (int f = 0; f < 10; ++f) v[f] = win[IMAP[f]];
        break;
    case 1:
        #pragma unroll
        for (int f = 0; f < 10; ++f) v[f] = win[LM0[f]];
        break;
    case 2:
        #pragma unroll
        for (int f = 0; f < 10; ++f) v[f] = win[LM1[f]];
        break;
    case 3:
        #pragma unroll
        for (int f = 0; f < 10; ++f) v[f] = win[RM0[f]];
        break;
    default:
        #pragma unroll
        for (int f = 0; f < 10; ++f) v[f] = win[RM1[f]];
        break;
    }
    #pragma unroll
    for (int o = 0; o < 2; ++o) {
        float l = 0.f, h = 0.f;
        #pragma unroll
        for (int k = 0; k < 8; ++k) {
            l = fmaf(v[2 * o + k], GL[k], l);
            h = fmaf(v[2 * o + k], GH[k], h);
        }
        lo[o] = l; hi[o] = h;
    }
}

__global__ __launch_bounds__(256)
void dwt2_db4_reg2(const float* __restrict__ x, float* __restrict__ out) {
    const int id   = blockIdx.x * 256 + threadIdx.x;
    const int cg   = id % NCG;
    const int rest = id / NCG;
    const int st   = rest % NS;
    const int bc   = rest / NS;
    const int c0   = 2 * cg;
    const int gb   = min(max(4 * cg - 8, 0), N - 12);  // 16B-aligned window base
    const int mode = (cg == 0) ? 1 : (cg == 1) ? 2 :
                     (cg == NCG - 2) ? 3 : (cg == NCG - 1) ? 4 : 0;
    const float* __restrict__ img = x + (size_t)bc * (N * N);
    const int eh0 = 2 * (st * TOH) + 1;

    f2 rlo[8], rhi[8];
    #pragma unroll
    for (int r = 0; r < 6; ++r)
        hconv(img + (size_t)ext_row(eh0 + r) * N + gb, mode, rlo[r], rhi[r]);

    const size_t sub = (size_t)NBC * HO * HO;
    float* __restrict__ obase = out + (size_t)bc * (HO * HO);

#define STEP(U) do {                                                          \
    const int uo_ = ob * 4 + (U);                                             \
    const int e_  = eh0 + 2 * uo_ + 6;                                        \
    hconv(img + (size_t)ext_row(e_)     * N + gb, mode,                       \
          rlo[(6 + 2 * (U)) & 7], rhi[(6 + 2 * (U)) & 7]);                    \
    hconv(img + (size_t)ext_row(e_ + 1) * N + gb, mode,                       \
          rlo[(7 + 2 * (U)) & 7], rhi[(7 + 2 * (U)) & 7]);                    \
    f2 ll = {0,0}, lh = {0,0}, hl = {0,0}, hh = {0,0};                        \
    _Pragma("unroll")                                                         \
    for (int k = 0; k < 8; ++k) {                                             \
        const f2 a_ = rlo[(2 * (U) + k) & 7];                                 \
        const f2 d_ = rhi[(2 * (U) + k) & 7];                                 \
        const float gl = GL[k], gh = GH[k];                                   \
        ll.x = fmaf(a_.x, gl, ll.x); ll.y = fmaf(a_.y, gl, ll.y);             \
        lh.x = fmaf(a_.x, gh, lh.x); lh.y = fmaf(a_.y, gh, lh.y);             \
        hl.x = fmaf(d_.x, gl, hl.x); hl.y = fmaf(d_.y, gl, hl.y);             \
        hh.x = fmaf(d_.x, gh, hh.x); hh.y = fmaf(d_.y, gh, hh.y);             \
    }                                                                         \
    const int ho_ = st * TOH + uo_;                                           \
    if (ho_ < HO) {                                                           \
        const size_t p = (size_t)ho_ * HO + c0;                               \
        if (cg != NCG - 1) {                                                  \
            *(f2u*)(obase + p)           = ll;                                \
            *(f2u*)(obase + sub + p)     = lh;                                \
            *(f2u*)(obase + 2 * sub + p) = hl;                                \
            *(f2u*)(obase + 3 * sub + p) = hh;                                \
        } else {                                                              \
            obase[p]           = ll.x;                                        \
            obase[sub + p]     = lh.x;                                        \
            obase[2 * sub + p] = hl.x;                                        \
            obase[3 * sub + p] = hh.x;                                        \
        }                                                                     \
    }                                                                         \
} while (0)

    for (int ob = 0; ob < TOH / 4; ++ob) {
        STEP(0); STEP(1); STEP(2); STEP(3);
    }
#undef STEP
}

} // namespace

extern "C" void kernel_launch(void* const* d_in, const int* in_sizes, int n_in,
                              void* d_out, int out_size, void* d_ws, size_t ws_size,
                              hipStream_t stream) {
    const float* x = (const float*)d_in[0];
    float* out = (float*)d_out;
    const int items  = NBC * NS * NCG;      // 732,160
    const int blocks = items / 256;         // 2860 (exact)
    dwt2_db4_reg2<<<blocks, 256, 0, stream>>>(x, out);
}

// Round 6
// 136.552 us; speedup vs baseline: 1.1237x; 1.1237x over previous
//
#include <hip/hip_runtime.h>

// Batched 2D db4 DWT (pywt dwt2, mode='symmetric') over [8,32,512,512] f32.
// Output [4, 8, 32, 259, 259] f32 (LL, LH, HL, HH).
//
//   y[o] = sum_k ext[2o+1+k] * G[k],  G[k] = F[7-k]
//   ext index j -> src:  j<7 -> 6-j ; j<=518 -> j-7 ; else 1030-j
//
// v6: register-streaming walker. Thread = (image, 12-row strip, 4 cols).
// Per mid-row r: prefetch row r+1 (4 aligned dwordx4, base 8cg-8 is
// 32B-aligned) into the alternate register buffer, hconv row r, scatter its
// lo/hi into 4 pending output accumulators (k = r - 2*uo), store+reset an
// accumulator when its k=7 tap lands. Depth-1 SW pipeline: next-row loads
// are in flight under ~300 cy of FMA. All indices macro-static. No LDS.

namespace {

constexpr int N    = 512;
constexpr int HO   = 259;
constexpr int NBC  = 256;
constexpr int TOH  = 12;                     // output rows per strip
constexpr int NS   = 22;                     // strips (22*12 = 264 >= 259)
constexpr int NCG  = 65;                     // 4-col groups
constexpr int MIDR = 2 * TOH + 6;            // 30 mid rows per strip

typedef float f4 __attribute__((ext_vector_type(4)));
typedef f4 __attribute__((aligned(4))) f4u;

__device__ constexpr float GL[8] = {
     0.23037781330885523f,  0.7148465705525415f,   0.6308807679295904f,
    -0.02798376941698385f, -0.18703481171888114f,  0.030841381835986965f,
     0.032883011666982945f,-0.010597401784997278f};
__device__ constexpr float GH[8] = {
    -0.010597401784997278f,-0.032883011666982945f, 0.030841381835986965f,
     0.18703481171888114f, -0.02798376941698385f, -0.6308807679295904f,
     0.7148465705525415f,  -0.23037781330885523f};

// Tap f -> index into the 16-float window loaded from clamped base.
// interior (base 8cg-8): tap f = win[2+f]
// cg==0   (base 0)     : ext[1+f]   -> {5,4,3,2,1,0,0,1,2,3,4,5,6,7}
// cg==64  (base 496)   : ext[513+f] -> {10,11,12,13,14,15,15,14,13,12,11,10,9,8}
__device__ constexpr int LMAP[14] = {5,4,3,2,1,0,0,1,2,3,4,5,6,7};
__device__ constexpr int RMAP[14] = {10,11,12,13,14,15,15,14,13,12,11,10,9,8};

__device__ __forceinline__ int ext_row(int j) {
    int v = j - 7;
    v = (j < 7)     ? (6 - j)         : v;
    v = (j > N + 6) ? (2 * N + 6 - j) : v;
    return v;
}

__device__ __forceinline__ void hconv16(const f4& A, const f4& B, const f4& C,
                                        const f4& D, int mode, f4& lo, f4& hi) {
    const float win[16] = {A.x,A.y,A.z,A.w, B.x,B.y,B.z,B.w,
                           C.x,C.y,C.z,C.w, D.x,D.y,D.z,D.w};
    float v[14];
    if (mode == 0) {
        #pragma unroll
        for (int f = 0; f < 14; ++f) v[f] = win[2 + f];
    } else if (mode < 0) {
        #pragma unroll
        for (int f = 0; f < 14; ++f) v[f] = win[LMAP[f]];
    } else {
        #pragma unroll
        for (int f = 0; f < 14; ++f) v[f] = win[RMAP[f]];
    }
    #pragma unroll
    for (int o = 0; o < 4; ++o) {
        float l = 0.f, h = 0.f;
        #pragma unroll
        for (int k = 0; k < 8; ++k) {
            l = fmaf(v[2 * o + k], GL[k], l);
            h = fmaf(v[2 * o + k], GH[k], h);
        }
        lo[o] = l; hi[o] = h;
    }
}

__global__ __launch_bounds__(256)
void dwt2_db4_stream(const float* __restrict__ x, float* __restrict__ out) {
    const int id   = blockIdx.x * 256 + threadIdx.x;
    const int cg   = id % NCG;
    const int rest = id / NCG;
    const int st   = rest % NS;
    const int bc   = rest / NS;
    const int c0   = 4 * cg;
    const int ab   = min(max(8 * cg - 8, 0), N - 16);   // 32B-aligned window base
    const int mode = (cg == 0) ? -1 : ((cg == NCG - 1) ? 1 : 0);
    const float* __restrict__ img = x + (size_t)bc * (N * N);
    const int eh0 = 2 * (st * TOH) + 1;
    const size_t sub = (size_t)NBC * HO * HO;
    float* __restrict__ obase = out + (size_t)bc * (HO * HO);

    // pending accumulators: P[slot][0..3] = ll, lh, hl, hh
    f4 P[4][4];
    #pragma unroll
    for (int s = 0; s < 4; ++s)
        #pragma unroll
        for (int q = 0; q < 4; ++q) P[s][q] = (f4){0.f, 0.f, 0.f, 0.f};

    f4 b0a, b0b, b0c, b0d, b1a, b1b, b1c, b1d;

#define PRE(rn_, A_, B_, C_, D_) do {                                         \
    const float* rp_ = img + (size_t)ext_row(eh0 + (rn_)) * N + ab;           \
    A_ = *(const f4*)(rp_);      B_ = *(const f4*)(rp_ + 4);                  \
    C_ = *(const f4*)(rp_ + 8);  D_ = *(const f4*)(rp_ + 12);                 \
} while (0)

#define UPD(r_, uo_) do { if ((uo_) >= 0 && (uo_) < TOH) {                    \
    const int kk_ = (r_) - 2 * (uo_);                                         \
    const int sl_ = (uo_) & 3;                                                \
    const float gl_ = GL[kk_], gh_ = GH[kk_];                                 \
    P[sl_][0] += lo * gl_;  P[sl_][1] += lo * gh_;                            \
    P[sl_][2] += hi * gl_;  P[sl_][3] += hi * gh_;                            \
} } while (0)

#define FIN(r_) do {                                                          \
    const int uo_ = ((r_) - 7) / 2;                                           \
    if (uo_ >= 0 && uo_ < TOH) {                                              \
        const int sl_ = uo_ & 3;                                              \
        const int ho_ = st * TOH + uo_;                                       \
        if (ho_ < HO) {                                                       \
            const size_t p_ = (size_t)ho_ * HO + c0;                          \
            if (cg != NCG - 1) {                                              \
                *(f4u*)(obase + p_)           = P[sl_][0];                    \
                *(f4u*)(obase + sub + p_)     = P[sl_][1];                    \
                *(f4u*)(obase + 2 * sub + p_) = P[sl_][2];                    \
                *(f4u*)(obase + 3 * sub + p_) = P[sl_][3];                    \
            } else {                                                          \
                _Pragma("unroll")                                             \
                for (int o = 0; o < 3; ++o) {                                 \
                    obase[p_ + o]           = P[sl_][0][o];                   \
                    obase[sub + p_ + o]     = P[sl_][1][o];                   \
                    obase[2 * sub + p_ + o] = P[sl_][2][o];                   \
                    obase[3 * sub + p_ + o] = P[sl_][3][o];                   \
                }                                                             \
            }                                                                 \
        }                                                                     \
        P[sl_][0] = (f4){0.f,0.f,0.f,0.f};  P[sl_][1] = (f4){0.f,0.f,0.f,0.f};\
        P[sl_][2] = (f4){0.f,0.f,0.f,0.f};  P[sl_][3] = (f4){0.f,0.f,0.f,0.f};\
    }                                                                         \
} while (0)

#define ROW(r_, CA_, CB_, CC_, CD_, NA_, NB_, NC_, ND_) do {                  \
    if ((r_) + 1 < MIDR) PRE((r_) + 1, NA_, NB_, NC_, ND_);                   \
    f4 lo, hi;                                                                \
    hconv16(CA_, CB_, CC_, CD_, mode, lo, hi);                                \
    if (((r_) & 1) == 0) {                                                    \
        UPD(r_, (r_) / 2);     UPD(r_, (r_) / 2 - 1);                         \
        UPD(r_, (r_) / 2 - 2); UPD(r_, (r_) / 2 - 3);                         \
    } else {                                                                  \
        UPD(r_, ((r_) - 1) / 2); UPD(r_, ((r_) - 3) / 2);                     \
        UPD(r_, ((r_) - 5) / 2); UPD(r_, ((r_) - 7) / 2);                     \
        FIN(r_);                                                              \
    }                                                                         \
} while (0)

#define ROW_E(r_) ROW(r_, b0a,b0b,b0c,b0d, b1a,b1b,b1c,b1d)
#define ROW_O(r_) ROW(r_, b1a,b1b,b1c,b1d, b0a,b0b,b0c,b0d)

    PRE(0, b0a, b0b, b0c, b0d);
    ROW_E(0);  ROW_O(1);  ROW_E(2);  ROW_O(3);  ROW_E(4);  ROW_O(5);
    ROW_E(6);  ROW_O(7);  ROW_E(8);  ROW_O(9);  ROW_E(10); ROW_O(11);
    ROW_E(12); ROW_O(13); ROW_E(14); ROW_O(15); ROW_E(16); ROW_O(17);
    ROW_E(18); ROW_O(19); ROW_E(20); ROW_O(21); ROW_E(22); ROW_O(23);
    ROW_E(24); ROW_O(25); ROW_E(26); ROW_O(27); ROW_E(28); ROW_O(29);

#undef ROW_E
#undef ROW_O
#undef ROW
#undef FIN
#undef UPD
#undef PRE
}

} // namespace

extern "C" void kernel_launch(void* const* d_in, const int* in_sizes, int n_in,
                              void* d_out, int out_size, void* d_ws, size_t ws_size,
                              hipStream_t stream) {
    const float* x = (const float*)d_in[0];
    float* out = (float*)d_out;
    const int items  = NBC * NS * NCG;      // 366,080
    const int blocks = items / 256;         // 1430 (exact)
    dwt2_db4_stream<<<blocks, 256, 0, stream>>>(x, out);
}